// Round 1
// baseline (137.104 us; speedup 1.0000x reference)
//
#include <hip/hip_runtime.h>
#include <math.h>

// Problem constants (B=2, C=64, inter=32, H=W=80 -> N=6400)
#define BATCH 2
#define CH    64
#define INTER 32
#define NPOS  6400
#define LOG2E 1.44269504088896f
#define SPLIT 10          // key-dim split factor
#define TPB   5           // 128-key tiles per split chunk (5*128*10 = 6400)

typedef _Float16 f16x8 __attribute__((ext_vector_type(8)));  // MFMA A/B frag
typedef _Float16 f16x2 __attribute__((ext_vector_type(2)));
typedef _Float16 h4    __attribute__((ext_vector_type(4)));
typedef float    f32x4 __attribute__((ext_vector_type(4)));  // MFMA C/D

// v_cvt_pkrtz returns __fp16x2; bit-identical to _Float16x2 -> bit_cast.
static __device__ __forceinline__ f16x2 pkrtz(float a, float b) {
    return __builtin_bit_cast(f16x2, __builtin_amdgcn_cvt_pkrtz(a, b));
}

// ---------------------------------------------------------------------------
// Kernel 1: projections -> fp16 workspace. Grid (N/64, 3, B); blockIdx.y:
//   0: theta -> Qh [b][n][32], scaled by log2(e)
//   1: phi   -> Kh [b][n][32]
//   2: g     -> Vt [b][32][N] with per-128-tile SLOT PERMUTATION:
//      key kk -> slot (g>>1)*32 + qd*8 + (g&1)*4 + rr  (g=kk>>4,
//      qd=(kk>>2)&3, rr=kk&3) so the flash kernel's register-resident P^T
//      lines up with V's A-fragment slots. (Ref-verified R7/R10/R12.)
// ---------------------------------------------------------------------------
__global__ __launch_bounds__(256) void nlb_proj_kernel(
    const float* __restrict__ x,
    const float* __restrict__ g_w,
    const float* __restrict__ th_w,
    const float* __restrict__ ph_w,
    _Float16* __restrict__ Qh, _Float16* __restrict__ Kh,
    _Float16* __restrict__ Vt)
{
    const int b  = blockIdx.z;
    const int p  = blockIdx.y;
    const int n0 = blockIdx.x * 64;
    const int t  = threadIdx.x;
    const int w  = __builtin_amdgcn_readfirstlane(t) >> 6;  // wave id (uniform)
    const int lane = t & 63;

    const float* wsrc = (p == 0) ? th_w : (p == 1) ? ph_w : g_w;
    const float* xg = x + (size_t)b * CH * NPOS + n0 + lane;

    float xr[64];
    #pragma unroll
    for (int c = 0; c < 64; c++) xr[c] = xg[(size_t)c * NPOS];

    __shared__ float buf[32][65];

    float accs[8];
    #pragma unroll
    for (int rr = 0; rr < 8; rr++) {
        const int row = w * 8 + rr;                  // wave-uniform
        const float* wr = wsrc + row * 64;           // -> scalar loads
        float a0 = 0.f, a1 = 0.f, a2 = 0.f, a3 = 0.f;
        #pragma unroll
        for (int c = 0; c < 16; c++) {
            a0 += wr[c]      * xr[c];
            a1 += wr[c + 16] * xr[c + 16];
            a2 += wr[c + 32] * xr[c + 32];
            a3 += wr[c + 48] * xr[c + 48];
        }
        accs[rr] = (a0 + a1) + (a2 + a3);
    }

    if (p == 2) {   // V^T with per-tile slot permutation
        const int n   = n0 + lane;
        const int kk  = n & 127;
        const int g   = kk >> 4, qd = (kk >> 2) & 3, rr2 = kk & 3;
        const int slot = (g >> 1) * 32 + qd * 8 + (g & 1) * 4 + rr2;
        const size_t col = (size_t)(n >> 7) * 128 + slot;
        #pragma unroll
        for (int rr = 0; rr < 8; rr++)
            Vt[((size_t)b * 32 + w * 8 + rr) * NPOS + col] = (_Float16)accs[rr];
        return;
    }

    #pragma unroll
    for (int rr = 0; rr < 8; rr++) buf[w * 8 + rr][lane] = accs[rr];
    __syncthreads();

    const float scale = (p == 0) ? LOG2E : 1.f;
    _Float16* dst = (p == 0) ? Qh : Kh;
    const int pos = t >> 2, ic = t & 3;   // 8 consecutive inter-ch per thread
    f16x8 hv;
    #pragma unroll
    for (int j = 0; j < 8; j++)
        hv[j] = (_Float16)(buf[ic * 8 + j][pos] * scale);
    *(f16x8*)(dst + ((size_t)b * NPOS + n0 + pos) * 32 + ic * 8) = hv;
}

// ---------------------------------------------------------------------------
// Kernel 2: fp16 MFMA flash attention, split-K, register-P transposed
// dataflow, NO LDS AND NO BARRIERS.  K/V are L2-resident (819 KB each per
// the whole problem; a 16 KB tile is shared by the block's 4 waves via L1),
// so LDS staging was pure overhead (guide common-mistake #7): 10 barriers
// per block + ~800 MB of LDS round-trip traffic.  Each wave now runs free:
//   K frags  : 1 KB fully-coalesced f16x8 loads per 16-key group.
//   V frags  : issued BEFORE the softmax so their latency hides under the
//              exp2 chain (slot permutation from kernel 1 keeps them
//              MFMA-ready).
// Grid (N/64, SPLIT, B) = 2000 blocks, 256 thr = 4 independent waves.
//   S^T = K Q^T : A = K frag (global), B = Q frag (regs).
//     C-layout: lane(n16,quad) holds S^T[key=g*16+quad*4+r][q=n16].
//   softmax: lane-local max tree + shfl_xor(16,32); l cross-quad deferred.
//   O^T = V^T P^T : A = V frag (global, slot-permuted), B = pb packed
//     from sc regs via v_cvt_pkrtz. P never leaves registers.
// ---------------------------------------------------------------------------
__global__ __launch_bounds__(256) void nlb_flash_kernel(
    const _Float16* __restrict__ Qh, const _Float16* __restrict__ Kh,
    const _Float16* __restrict__ Vt,
    _Float16* __restrict__ Opart, float2* __restrict__ ml)
{
    const int b     = blockIdx.z;
    const int split = blockIdx.y;
    const int t     = threadIdx.x;
    const int w     = t >> 6;
    const int lane  = t & 63;
    const int n16   = lane & 15;
    const int quad  = lane >> 4;
    const int q0    = blockIdx.x * 64 + w * 16;

    // Q fragment (B-operand of Q^T)
    const f16x8 qa = *(const f16x8*)(Qh + ((size_t)b * NPOS + q0 + n16) * 32 + quad * 8);

    // per-lane base pointers for direct-from-cache fragment loads
    //   K frag g of tile k0:  kp + (k0 + g*16)*32      (was ks[g*16+n16][quad*8])
    //   V frag kc of tile k0: vp + k0 + kc*32          (was vs[n16][kc*32+quad*8])
    //                         vp + 16*NPOS + k0 + kc*32 (was vs[16+n16][...])
    const _Float16* kp = Kh + (size_t)b * NPOS * 32 + (size_t)n16 * 32 + quad * 8;
    const _Float16* vp = Vt + ((size_t)b * 32 + n16) * NPOS + quad * 8;

    f32x4 o0 = (f32x4)0.f;              // dims quad*4+r      (query n16)
    f32x4 o1 = (f32x4)0.f;              // dims 16+quad*4+r
    float runm = -1e30f, lsum = 0.f;    // per-lane state for query n16

    const int k0base = split * TPB * 128;

    for (int i = 0; i < TPB; i++) {
        const int k0 = k0base + i * 128;

        // S^T = K Q^T  (K frags straight from L1/L2)
        f16x8 kr[8];
        #pragma unroll
        for (int g = 0; g < 8; g++)
            kr[g] = *(const f16x8*)(kp + (size_t)(k0 + g * 16) * 32);

        f32x4 sc[8];
        #pragma unroll
        for (int g = 0; g < 8; g++) {
            f32x4 z = (f32x4)0.f;
            sc[g] = __builtin_amdgcn_mfma_f32_16x16x32_f16(kr[g], qa, z, 0, 0, 0);
        }

        // V frags issued now; latency hides under the softmax below
        f16x8 vr0[4], vr1[4];
        #pragma unroll
        for (int kc = 0; kc < 4; kc++) {
            vr0[kc] = *(const f16x8*)(vp + k0 + kc * 32);
            vr1[kc] = *(const f16x8*)(vp + (size_t)16 * NPOS + k0 + kc * 32);
        }

        // softmax over this query's 128 keys (lane owns 32; rest in n16+16k)
        float m = fmaxf(fmaxf(sc[0][0], sc[0][1]), fmaxf(sc[0][2], sc[0][3]));
        #pragma unroll
        for (int g = 1; g < 8; g++) {
            float mg = fmaxf(fmaxf(sc[g][0], sc[g][1]), fmaxf(sc[g][2], sc[g][3]));
            m = fmaxf(m, mg);
        }
        m = fmaxf(m, __shfl_xor(m, 16));
        m = fmaxf(m, __shfl_xor(m, 32));
        float nm = fmaxf(runm, m);
        float a  = __builtin_amdgcn_exp2f(runm - nm);
        runm = nm;
        float ls = 0.f;
        #pragma unroll
        for (int g = 0; g < 8; g++) {
            #pragma unroll
            for (int r = 0; r < 4; r++) {
                float p = __builtin_amdgcn_exp2f(sc[g][r] - nm);
                sc[g][r] = p;
                ls += p;
            }
        }
        lsum = lsum * a + ls;   // cross-quad sum deferred to epilogue
        o0 *= a;
        o1 *= a;

        // O^T += V^T P^T : pb[j] = P[key (kc*2+(j>>2))*16+quad*4+(j&3)]
        #pragma unroll
        for (int kc = 0; kc < 4; kc++) {
            union { f16x8 v; f16x2 h2[4]; } pb;
            pb.h2[0] = pkrtz(sc[kc * 2][0],     sc[kc * 2][1]);
            pb.h2[1] = pkrtz(sc[kc * 2][2],     sc[kc * 2][3]);
            pb.h2[2] = pkrtz(sc[kc * 2 + 1][0], sc[kc * 2 + 1][1]);
            pb.h2[3] = pkrtz(sc[kc * 2 + 1][2], sc[kc * 2 + 1][3]);
            o0 = __builtin_amdgcn_mfma_f32_16x16x32_f16(vr0[kc], pb.v, o0, 0, 0, 0);
            o1 = __builtin_amdgcn_mfma_f32_16x16x32_f16(vr1[kc], pb.v, o1, 0, 0, 0);
        }
    }

    // epilogue: finish l across quads, normalize, store O^T + (m,l)
    lsum += __shfl_xor(lsum, 16);
    lsum += __shfl_xor(lsum, 32);
    float invl = 1.f / lsum;
    const size_t base = ((size_t)(b * SPLIT + split) * NPOS + q0 + n16) * 32;
    h4 h0, h1;
    #pragma unroll
    for (int r = 0; r < 4; r++) {
        h0[r] = (_Float16)(o0[r] * invl);
        h1[r] = (_Float16)(o1[r] * invl);
    }
    *(h4*)(Opart + base + quad * 4)      = h0;
    *(h4*)(Opart + base + 16 + quad * 4) = h1;
    if (quad == 0)
        ml[(size_t)(b * SPLIT + split) * NPOS + q0 + n16] = make_float2(runm, lsum);
}

// ---------------------------------------------------------------------------
// Kernel 3: flash-combine the SPLIT partials + W-projection + residual.
// Grid (N/32, B). Opart layout [b][split][q][32] -> coalesced 8B reads.
// ---------------------------------------------------------------------------
__global__ __launch_bounds__(256) void nlb_combine_kernel(
    const _Float16* __restrict__ Opart, const float2* __restrict__ ml,
    const float* __restrict__ w_w, const float* __restrict__ x,
    float* __restrict__ out)
{
    __shared__ float wf[64][33];
    __shared__ float wts[32][12];
    __shared__ float of[32][33];

    const int b  = blockIdx.y;
    const int q0 = blockIdx.x * 32;
    const int t  = threadIdx.x;

    for (int idx = t; idx < 2048; idx += 256) wf[idx >> 5][idx & 31] = w_w[idx];

    if (t < 32) {   // merge coefficients c_s = exp2(m_s-m*)*l_s / sum
        float2 v[SPLIT];
        float m = -1e30f;
        #pragma unroll
        for (int s = 0; s < SPLIT; s++) {
            v[s] = ml[(size_t)(b * SPLIT + s) * NPOS + q0 + t];
            m = fmaxf(m, v[s].x);
        }
        float suml = 0.f;
        #pragma unroll
        for (int s = 0; s < SPLIT; s++) {
            float wgt = __builtin_amdgcn_exp2f(v[s].x - m) * v[s].y;
            wts[t][s] = wgt;
            suml += wgt;
        }
        float inv = 1.f / suml;
        #pragma unroll
        for (int s = 0; s < SPLIT; s++) wts[t][s] *= inv;
    }
    __syncthreads();

    {   // merge partial O: thread -> (q = t>>3, dims dg*4..dg*4+3) COALESCED
        const int q = t >> 3, dg = t & 7;
        float a0 = 0.f, a1 = 0.f, a2 = 0.f, a3 = 0.f;
        #pragma unroll
        for (int s = 0; s < SPLIT; s++) {
            h4 hv = *(const h4*)(Opart +
                ((size_t)(b * SPLIT + s) * NPOS + q0 + q) * 32 + dg * 4);
            float c = wts[q][s];
            a0 += c * (float)hv[0]; a1 += c * (float)hv[1];
            a2 += c * (float)hv[2]; a3 += c * (float)hv[3];
        }
        of[q][dg * 4]     = a0; of[q][dg * 4 + 1] = a1;
        of[q][dg * 4 + 2] = a2; of[q][dg * 4 + 3] = a3;
    }
    __syncthreads();

    {   // y = W o + x: thread -> (query, 8 channels)
        const int q = t & 31, cg = t >> 5;
        const float* xb = x   + (size_t)b * CH * NPOS + q0 + q;
        float*       ob = out + (size_t)b * CH * NPOS + q0 + q;
        #pragma unroll
        for (int cc = 0; cc < 8; cc++) {
            int ch = cg * 8 + cc;
            float acc = 0.f;
            #pragma unroll
            for (int i = 0; i < 32; i++) acc += wf[ch][i] * of[q][i];
            ob[(size_t)ch * NPOS] = acc + xb[(size_t)ch * NPOS];
        }
    }
}

extern "C" void kernel_launch(void* const* d_in, const int* in_sizes, int n_in,
                              void* d_out, int out_size, void* d_ws, size_t ws_size,
                              hipStream_t stream) {
    const float* x    = (const float*)d_in[0];
    const float* g_w  = (const float*)d_in[1];
    const float* th_w = (const float*)d_in[2];
    const float* ph_w = (const float*)d_in[3];
    const float* w_w  = (const float*)d_in[4];
    float* out = (float*)d_out;

    const size_t SZ = (size_t)BATCH * NPOS * INTER;   // 409600 elements
    _Float16* Qh = (_Float16*)d_ws;
    _Float16* Kh = Qh + SZ;
    _Float16* Vt = Kh + SZ;
    _Float16* Opart = Vt + SZ;                         // [B][SPLIT][N][32]
    float2*   ml    = (float2*)(Opart + SZ * SPLIT);   // [B][SPLIT][N]

    nlb_proj_kernel<<<dim3(NPOS / 64, 3, BATCH), 256, 0, stream>>>(
        x, g_w, th_w, ph_w, Qh, Kh, Vt);
    nlb_flash_kernel<<<dim3(NPOS / 64, SPLIT, BATCH), 256, 0, stream>>>(
        Qh, Kh, Vt, Opart, ml);
    nlb_combine_kernel<<<dim3(NPOS / 32, BATCH), 256, 0, stream>>>(
        Opart, ml, w_w, x, out);
}

// Round 2
// 102.209 us; speedup vs baseline: 1.3414x; 1.3414x over previous
//
#include <hip/hip_runtime.h>
#include <math.h>

// Problem constants (B=2, C=64, inter=32, H=W=80 -> N=6400)
#define BATCH 2
#define CH    64
#define INTER 32
#define NPOS  6400
#define NTILE 50          // N / 128 key tiles per batch
#define LOG2E 1.44269504088896f
#define SPLIT 10          // key-dim split factor
#define TPB   5           // 128-key tiles per split chunk (5*128*10 = 6400)

typedef _Float16 f16x8 __attribute__((ext_vector_type(8)));  // MFMA A/B frag
typedef _Float16 f16x2 __attribute__((ext_vector_type(2)));
typedef _Float16 h4    __attribute__((ext_vector_type(4)));
typedef float    f32x4 __attribute__((ext_vector_type(4)));  // MFMA C/D

// v_cvt_pkrtz returns __fp16x2; bit-identical to _Float16x2 -> bit_cast.
static __device__ __forceinline__ f16x2 pkrtz(float a, float b) {
    return __builtin_bit_cast(f16x2, __builtin_amdgcn_cvt_pkrtz(a, b));
}

// ---------------------------------------------------------------------------
// FRAGMENT-PACKED K/V layout (new this round).  For each 128-key tile T the
// flash kernel consumes exactly 8 K-fragments and 8 V-fragments, each a
// 64-lane x 16B wave read.  We store them EXACTLY in that order in DRAM:
//   Kf unit index ((b*50+T)*8 + g)*64 + lane, 16B units, where
//     lane = quad*16 + n16 holds K[key=T*128+g*16+n16][dims quad*8..+7].
//   Vf unit index ((b*50+T)*8 + kc*2+half)*64 + lane, where
//     lane = qd*16 + d15 holds V^T[dim=half*16+d15][slots kc*32+qd*8..+7],
//     slot(kk) = (g>>1)*32 + qd*8 + (g&1)*4 + rr  (verified R7/R10/R12 perm).
// Staging in the flash kernel is then two contiguous 40KB copies and every
// LDS read is a sequential conflict-free ds_read_b128.
// ---------------------------------------------------------------------------

// ---------------------------------------------------------------------------
// Kernel 1: projections -> fp16 workspace. Grid (N/64, 3, B); blockIdx.y:
//   0: theta -> Qh [b][n][32] (linear), scaled by log2(e)
//   1: phi   -> Kf fragment-packed (see above)
//   2: g     -> Vf fragment-packed (see above)
// ---------------------------------------------------------------------------
__global__ __launch_bounds__(256) void nlb_proj_kernel(
    const float* __restrict__ x,
    const float* __restrict__ g_w,
    const float* __restrict__ th_w,
    const float* __restrict__ ph_w,
    _Float16* __restrict__ Qh, _Float16* __restrict__ Kf,
    _Float16* __restrict__ Vf)
{
    const int b  = blockIdx.z;
    const int p  = blockIdx.y;
    const int n0 = blockIdx.x * 64;
    const int t  = threadIdx.x;
    const int w  = __builtin_amdgcn_readfirstlane(t) >> 6;  // wave id (uniform)
    const int lane = t & 63;

    const float* wsrc = (p == 0) ? th_w : (p == 1) ? ph_w : g_w;
    const float* xg = x + (size_t)b * CH * NPOS + n0 + lane;

    float xr[64];
    #pragma unroll
    for (int c = 0; c < 64; c++) xr[c] = xg[(size_t)c * NPOS];

    __shared__ float buf[32][65];

    float accs[8];
    #pragma unroll
    for (int rr = 0; rr < 8; rr++) {
        const int row = w * 8 + rr;                  // wave-uniform
        const float* wr = wsrc + row * 64;           // -> scalar loads
        float a0 = 0.f, a1 = 0.f, a2 = 0.f, a3 = 0.f;
        #pragma unroll
        for (int c = 0; c < 16; c++) {
            a0 += wr[c]      * xr[c];
            a1 += wr[c + 16] * xr[c + 16];
            a2 += wr[c + 32] * xr[c + 32];
            a3 += wr[c + 48] * xr[c + 48];
        }
        accs[rr] = (a0 + a1) + (a2 + a3);
    }

    if (p == 2) {   // V -> fragment-packed Vf
        const int n  = n0 + lane;
        const int T  = n >> 7, kk = n & 127;
        const int g  = kk >> 4, qd = (kk >> 2) & 3, r3 = kk & 3;
        const int kc = g >> 1, j = (g & 1) * 4 + r3;
        const int half = w >> 1, d15base = (w & 1) * 8;
        // element addr = (((b*50+T)*8 + kc*2+half)*64 + qd*16 + d15)*8 + j
        _Float16* vb = Vf +
            (((((size_t)b * NTILE + T) * 8 + kc * 2 + half) * 64
              + qd * 16 + d15base) * 8 + j);
        #pragma unroll
        for (int rr = 0; rr < 8; rr++)
            vb[(size_t)rr * 8] = (_Float16)accs[rr];   // d15 += 1 -> +8 elems
        return;
    }

    #pragma unroll
    for (int rr = 0; rr < 8; rr++) buf[w * 8 + rr][lane] = accs[rr];
    __syncthreads();

    const int pos = t >> 2, ic = t & 3;   // 8 consecutive inter-ch per thread
    if (p == 0) {
        f16x8 hv;
        #pragma unroll
        for (int j = 0; j < 8; j++)
            hv[j] = (_Float16)(buf[ic * 8 + j][pos] * LOG2E);
        *(f16x8*)(Qh + ((size_t)b * NPOS + n0 + pos) * 32 + ic * 8) = hv;
    } else {      // K -> fragment-packed Kf
        f16x8 hv;
        #pragma unroll
        for (int j = 0; j < 8; j++)
            hv[j] = (_Float16)buf[ic * 8 + j][pos];
        const int key = n0 + pos, T = key >> 7, kk = key & 127;
        const int g = kk >> 4, m16 = kk & 15;
        ((f16x8*)Kf)[(((size_t)b * NTILE + T) * 8 + g) * 64 + ic * 16 + m16] = hv;
    }
}

// ---------------------------------------------------------------------------
// Kernel 2: fp16 MFMA flash attention, split-K, register-P dataflow.
// ONE barrier per block: the whole 640-key chunk (5 tiles of K + V,
// fragment-packed) is bulk-staged into 80KB of LDS as two contiguous 40KB
// copies, then 5 tiles of pure LDS-fed compute run with NO further sync —
// the compiler pipelines ds_reads across tiles freely.  R0's version paid
// 2 barriers per tile (10 rendezvous + vmcnt drains per block); R1 showed
// the kernel is latency-bound (MfmaUtil 6.5%), not bandwidth-bound.
// Grid (N/128, SPLIT, B) = 1000 blocks, 512 thr = 8 waves x 16 queries.
// 80KB LDS -> 2 blocks/CU, 16 waves/CU; staging stall of one block
// overlaps the other block's compute.
//   S^T = K Q^T : A = K frag (LDS, sequential read), B = Q frag (regs).
//     C-layout: lane(n16,quad) holds S^T[key=g*16+quad*4+r][q=n16].
//   softmax: lane-local max tree + shfl_xor(16,32); l cross-quad deferred.
//   O^T = V^T P^T : A = V frag (LDS, slot-permuted by proj), B = pb packed
//     from sc regs via v_cvt_pkrtz. P never touches LDS.
// ---------------------------------------------------------------------------
__global__ __launch_bounds__(512) void nlb_flash_kernel(
    const _Float16* __restrict__ Qh, const _Float16* __restrict__ Kf,
    const _Float16* __restrict__ Vf,
    _Float16* __restrict__ Opart, float2* __restrict__ ml)
{
    __shared__ f16x8 smem[5120];   // 80KB: [0,2560) = K units, [2560,5120) = V

    const int b     = blockIdx.z;
    const int split = blockIdx.y;
    const int t     = threadIdx.x;
    const int w     = t >> 6;
    const int lane  = t & 63;
    const int n16   = lane & 15;
    const int quad  = lane >> 4;
    const int q0    = blockIdx.x * 128 + w * 16;

    // Q fragment (B-operand of Q^T) — issued before staging, lands under it
    const f16x8 qa = *(const f16x8*)(Qh + ((size_t)b * NPOS + q0 + n16) * 32 + quad * 8);

    // bulk stage: 2 contiguous 40KB fragment-packed copies (16B/thread x 5)
    {
        const f16x8* Ks = (const f16x8*)Kf + ((size_t)b * NTILE + split * TPB) * 512;
        const f16x8* Vs = (const f16x8*)Vf + ((size_t)b * NTILE + split * TPB) * 512;
        f16x8 st[5];
        #pragma unroll
        for (int c = 0; c < 5; c++) st[c] = Ks[c * 512 + t];
        #pragma unroll
        for (int c = 0; c < 5; c++) smem[c * 512 + t] = st[c];
        #pragma unroll
        for (int c = 0; c < 5; c++) st[c] = Vs[c * 512 + t];
        #pragma unroll
        for (int c = 0; c < 5; c++) smem[2560 + c * 512 + t] = st[c];
    }
    __syncthreads();   // the ONLY barrier in this kernel

    f32x4 o0 = (f32x4)0.f;              // dims quad*4+r      (query n16)
    f32x4 o1 = (f32x4)0.f;              // dims 16+quad*4+r
    float runm = -1e30f, lsum = 0.f;    // per-lane state for query n16

    for (int i = 0; i < TPB; i++) {
        const int kb = i * 512;          // K units of tile i
        const int vb = 2560 + i * 512;   // V units of tile i

        // S^T = K Q^T  (sequential conflict-free ds_read_b128)
        f32x4 sc[8];
        #pragma unroll
        for (int g = 0; g < 8; g++) {
            f16x8 kf = smem[kb + g * 64 + lane];
            f32x4 z = (f32x4)0.f;
            sc[g] = __builtin_amdgcn_mfma_f32_16x16x32_f16(kf, qa, z, 0, 0, 0);
        }

        // softmax over this query's 128 keys (lane owns 32; rest in n16+16k)
        float m = fmaxf(fmaxf(sc[0][0], sc[0][1]), fmaxf(sc[0][2], sc[0][3]));
        #pragma unroll
        for (int g = 1; g < 8; g++) {
            float mg = fmaxf(fmaxf(sc[g][0], sc[g][1]), fmaxf(sc[g][2], sc[g][3]));
            m = fmaxf(m, mg);
        }
        m = fmaxf(m, __shfl_xor(m, 16));
        m = fmaxf(m, __shfl_xor(m, 32));
        float nm = fmaxf(runm, m);
        float a  = __builtin_amdgcn_exp2f(runm - nm);
        runm = nm;
        float ls = 0.f;
        #pragma unroll
        for (int g = 0; g < 8; g++) {
            #pragma unroll
            for (int r = 0; r < 4; r++) {
                float p = __builtin_amdgcn_exp2f(sc[g][r] - nm);
                sc[g][r] = p;
                ls += p;
            }
        }
        lsum = lsum * a + ls;   // cross-quad sum deferred to epilogue
        o0 *= a;
        o1 *= a;

        // O^T += V^T P^T : pb[j] = P[key (kc*2+(j>>2))*16+quad*4+(j&3)]
        #pragma unroll
        for (int kc = 0; kc < 4; kc++) {
            union { f16x8 v; f16x2 h2[4]; } pb;
            pb.h2[0] = pkrtz(sc[kc * 2][0],     sc[kc * 2][1]);
            pb.h2[1] = pkrtz(sc[kc * 2][2],     sc[kc * 2][3]);
            pb.h2[2] = pkrtz(sc[kc * 2 + 1][0], sc[kc * 2 + 1][1]);
            pb.h2[3] = pkrtz(sc[kc * 2 + 1][2], sc[kc * 2 + 1][3]);
            f16x8 v0 = smem[vb + (kc * 2) * 64 + lane];       // dims 0..15
            f16x8 v1 = smem[vb + (kc * 2 + 1) * 64 + lane];   // dims 16..31
            o0 = __builtin_amdgcn_mfma_f32_16x16x32_f16(v0, pb.v, o0, 0, 0, 0);
            o1 = __builtin_amdgcn_mfma_f32_16x16x32_f16(v1, pb.v, o1, 0, 0, 0);
        }
    }

    // epilogue: finish l across quads, normalize, store O^T + (m,l)
    lsum += __shfl_xor(lsum, 16);
    lsum += __shfl_xor(lsum, 32);
    float invl = 1.f / lsum;
    const size_t base = ((size_t)(b * SPLIT + split) * NPOS + q0 + n16) * 32;
    h4 h0, h1;
    #pragma unroll
    for (int r = 0; r < 4; r++) {
        h0[r] = (_Float16)(o0[r] * invl);
        h1[r] = (_Float16)(o1[r] * invl);
    }
    *(h4*)(Opart + base + quad * 4)      = h0;
    *(h4*)(Opart + base + 16 + quad * 4) = h1;
    if (quad == 0)
        ml[(size_t)(b * SPLIT + split) * NPOS + q0 + n16] = make_float2(runm, lsum);
}

// ---------------------------------------------------------------------------
// Kernel 3: flash-combine the SPLIT partials + W-projection + residual.
// Grid (N/32, B). Opart layout [b][split][q][32] -> coalesced 8B reads.
// ---------------------------------------------------------------------------
__global__ __launch_bounds__(256) void nlb_combine_kernel(
    const _Float16* __restrict__ Opart, const float2* __restrict__ ml,
    const float* __restrict__ w_w, const float* __restrict__ x,
    float* __restrict__ out)
{
    __shared__ float wf[64][33];
    __shared__ float wts[32][12];
    __shared__ float of[32][33];

    const int b  = blockIdx.y;
    const int q0 = blockIdx.x * 32;
    const int t  = threadIdx.x;

    for (int idx = t; idx < 2048; idx += 256) wf[idx >> 5][idx & 31] = w_w[idx];

    if (t < 32) {   // merge coefficients c_s = exp2(m_s-m*)*l_s / sum
        float2 v[SPLIT];
        float m = -1e30f;
        #pragma unroll
        for (int s = 0; s < SPLIT; s++) {
            v[s] = ml[(size_t)(b * SPLIT + s) * NPOS + q0 + t];
            m = fmaxf(m, v[s].x);
        }
        float suml = 0.f;
        #pragma unroll
        for (int s = 0; s < SPLIT; s++) {
            float wgt = __builtin_amdgcn_exp2f(v[s].x - m) * v[s].y;
            wts[t][s] = wgt;
            suml += wgt;
        }
        float inv = 1.f / suml;
        #pragma unroll
        for (int s = 0; s < SPLIT; s++) wts[t][s] *= inv;
    }
    __syncthreads();

    {   // merge partial O: thread -> (q = t>>3, dims dg*4..dg*4+3) COALESCED
        const int q = t >> 3, dg = t & 7;
        float a0 = 0.f, a1 = 0.f, a2 = 0.f, a3 = 0.f;
        #pragma unroll
        for (int s = 0; s < SPLIT; s++) {
            h4 hv = *(const h4*)(Opart +
                ((size_t)(b * SPLIT + s) * NPOS + q0 + q) * 32 + dg * 4);
            float c = wts[q][s];
            a0 += c * (float)hv[0]; a1 += c * (float)hv[1];
            a2 += c * (float)hv[2]; a3 += c * (float)hv[3];
        }
        of[q][dg * 4]     = a0; of[q][dg * 4 + 1] = a1;
        of[q][dg * 4 + 2] = a2; of[q][dg * 4 + 3] = a3;
    }
    __syncthreads();

    {   // y = W o + x: thread -> (query, 8 channels)
        const int q = t & 31, cg = t >> 5;
        const float* xb = x   + (size_t)b * CH * NPOS + q0 + q;
        float*       ob = out + (size_t)b * CH * NPOS + q0 + q;
        #pragma unroll
        for (int cc = 0; cc < 8; cc++) {
            int ch = cg * 8 + cc;
            float acc = 0.f;
            #pragma unroll
            for (int i = 0; i < 32; i++) acc += wf[ch][i] * of[q][i];
            ob[(size_t)ch * NPOS] = acc + xb[(size_t)ch * NPOS];
        }
    }
}

extern "C" void kernel_launch(void* const* d_in, const int* in_sizes, int n_in,
                              void* d_out, int out_size, void* d_ws, size_t ws_size,
                              hipStream_t stream) {
    const float* x    = (const float*)d_in[0];
    const float* g_w  = (const float*)d_in[1];
    const float* th_w = (const float*)d_in[2];
    const float* ph_w = (const float*)d_in[3];
    const float* w_w  = (const float*)d_in[4];
    float* out = (float*)d_out;

    const size_t SZ = (size_t)BATCH * NPOS * INTER;   // 409600 elements
    _Float16* Qh = (_Float16*)d_ws;
    _Float16* Kf = Qh + SZ;
    _Float16* Vf = Kf + SZ;
    _Float16* Opart = Vf + SZ;                         // [B][SPLIT][N][32]
    float2*   ml    = (float2*)(Opart + SZ * SPLIT);   // [B][SPLIT][N]

    nlb_proj_kernel<<<dim3(NPOS / 64, 3, BATCH), 256, 0, stream>>>(
        x, g_w, th_w, ph_w, Qh, Kf, Vf);
    nlb_flash_kernel<<<dim3(NPOS / 128, SPLIT, BATCH), 512, 0, stream>>>(
        Qh, Kf, Vf, Opart, ml);
    nlb_combine_kernel<<<dim3(NPOS / 32, BATCH), 256, 0, stream>>>(
        Opart, ml, w_w, x, out);
}